// Round 12
// baseline (275.350 us; speedup 1.0000x reference)
//
#include <hip/hip_runtime.h>
#include <hip/hip_bf16.h>

#define DDIM   256
#define KNBR   16
#define TWOD   512
#define NTHREADS 256

using bf16x8  = __attribute__((ext_vector_type(8))) short;
using short4v = __attribute__((ext_vector_type(4))) short;
using f32x4   = __attribute__((ext_vector_type(4))) float;

#define WS_NEED  327680u   // WF shorts [0,163840): WqF(32) WkF(32) WgF(256)

__device__ __forceinline__ short f2bf(float x) {
  unsigned int u;
  __builtin_memcpy(&u, &x, 4);
  u += 0x7FFFu + ((u >> 16) & 1u);   // RNE
  return (short)(u >> 16);
}
__device__ __forceinline__ float bf2f(short s) {
  unsigned int u = ((unsigned int)(unsigned short)s) << 16;
  float f;
  __builtin_memcpy(&f, &u, 4);
  return f;
}

// Verified B-fragment loader (fallback path only)
__device__ __forceinline__ bf16x8 ldWfrag(const float* __restrict__ W, int ld, int r, int c) {
  const float4* p = (const float4*)(W + (size_t)r * ld + c);
  float4 a = p[0];
  float4 b = p[1];
  bf16x8 o;
  o[0] = f2bf(a.x); o[1] = f2bf(a.y); o[2] = f2bf(a.z); o[3] = f2bf(a.w);
  o[4] = f2bf(b.x); o[5] = f2bf(b.y); o[6] = f2bf(b.z); o[7] = f2bf(b.w);
  return o;
}

// ---- prep_frags: VERBATIM (HW-passed). WqF(32) WkF(32) WgF(256) ----
__global__ void prep_frags(const float* __restrict__ Wq,
                           const float* __restrict__ Wk,
                           const float* __restrict__ Wg,
                           short* __restrict__ F) {
  const int gid  = blockIdx.x * NTHREADS + threadIdx.x;
  const int lane = gid & 63;
  const int n16  = lane & 15;
  const int g4   = lane >> 4;
  const int f    = gid >> 6;                 // 0..319
  const float* src;
  short* dst;
  if (f < 32) {
    const int t = f >> 3, s = f & 7;
    src = Wq + (size_t)(t * 16 + n16) * DDIM + s * 32 + g4 * 8;
    dst = F + f * 512 + lane * 8;
  } else if (f < 64) {
    const int fq = f - 32;
    const int t = fq >> 3, s = fq & 7;
    src = Wk + (size_t)(t * 16 + n16) * DDIM + s * 32 + g4 * 8;
    dst = F + 16384 + fq * 512 + lane * 8;
  } else {
    const int fg = f - 64;                   // 0..255
    const int t4 = fg >> 4, s = fg & 15;
    src = Wg + (size_t)(t4 * 16 + n16) * TWOD + s * 32 + g4 * 8;
    dst = F + 32768 + fg * 512 + lane * 8;
  }
  float4 a = *(const float4*)src;
  float4 b = *(const float4*)(src + 4);
  bf16x8 o;
  o[0] = f2bf(a.x); o[1] = f2bf(a.y); o[2] = f2bf(a.z); o[3] = f2bf(a.w);
  o[4] = f2bf(b.x); o[5] = f2bf(b.y); o[6] = f2bf(b.z); o[7] = f2bf(b.w);
  *(bf16x8*)dst = o;
}

// ==================== natt_one: fully fused, DMA neighbor staging, 1 row/wave ====================
// LDS: sNbrF 64KB (4 waves x [16][256] f32, src-swizzled) | sCen [4][256] bf16 (2KB)
//      sGate [4][512] bf16 [cen|ctx] (4KB).  One barrier total (before gate GEMM).
__global__ __launch_bounds__(NTHREADS, 2)
void natt_one(const float* __restrict__ center, const float* __restrict__ neigh,
              const float* __restrict__ nwts, const void* __restrict__ vmask,
              const short* __restrict__ WF,
              const float* __restrict__ bq, const float* __restrict__ bk,
              const float* __restrict__ bg, float* __restrict__ out) {
  __shared__ __align__(16) float sNbrF[16384];
  __shared__ __align__(16) short sCen[1024];
  __shared__ __align__(16) short sGate[2048];
  const int tid  = threadIdx.x;
  const int lane = tid & 63;
  const int w    = tid >> 6;
  const int n16  = lane & 15;
  const int g4   = lane >> 4;
  const int row0 = blockIdx.x * 4;
  const size_t gr = (size_t)row0 + w;
  const unsigned char* mb = (const unsigned char*)vmask;
  const short* WqF = WF;
  const short* WkF = WF + 16384;
  const short* WgF = WF + 32768;

  // ---- 1. issue 16 async global->LDS row DMAs FIRST (r11-verified mechanics) ----
  const float* nbase = neigh + gr * (size_t)(KNBR * DDIM);
  #pragma unroll
  for (int j = 0; j < 16; ++j) {
    const float* gsrc = nbase + j * 256 + ((lane * 4) ^ ((j & 7) << 2));
    float* ldst = &sNbrF[w * 4096 + j * 256];   // wave-uniform base; HW adds lane*16
    __builtin_amdgcn_global_load_lds((const __attribute__((address_space(1))) void*)gsrc,
                                     (__attribute__((address_space(3))) void*)ldst,
                                     16, 0, 0);
  }

  // ---- 2. center row w -> sCen (own row) + sGate cen-half (r10-verified form) ----
  {
    float4 cv = *(const float4*)(center + gr * DDIM + lane * 4);
    short4v o;
    o[0] = f2bf(cv.x); o[1] = f2bf(cv.y); o[2] = f2bf(cv.z); o[3] = f2bf(cv.w);
    *(short4v*)&sCen[(w * 256 + lane * 4) ^ (w << 3)] = o;
    *(short4v*)&sGate[(w * 512 + lane * 4) ^ (w << 3)] = o;
  }

  // valid_mask dtype detection (verified)
  const unsigned char x1 = mb[lane * 4 + 1];
  const unsigned char x2 = mb[lane * 4 + 2];
  const unsigned char x3 = mb[lane * 4 + 3];
  const bool anyGe2 = __ballot((x1 >= 2) || (x2 >= 2) || (x3 >= 2)) != 0ULL;
  const bool anyNz  = __ballot(((x1 | x2) | x3) != 0) != 0ULL;
  const bool maskIsByte = anyNz && !anyGe2;

  // ---- 3. own-row q-projection (barrier-free; overlaps DMA latency) ----
  // All 16 A-rows = center row w -> every C/D row holds q[row w]; no shfl needed.
  f32x4 qacc[4];
  #pragma unroll
  for (int t = 0; t < 4; ++t) { qacc[t][0]=0.f; qacc[t][1]=0.f; qacc[t][2]=0.f; qacc[t][3]=0.f; }
  #pragma unroll
  for (int s = 0; s < 8; ++s) {
    bf16x8 af = *(const bf16x8*)&sCen[(w * 256 + s * 32 + g4 * 8) ^ (w << 3)];  // wave-uniform row
    #pragma unroll
    for (int t = 0; t < 4; ++t) {
      bf16x8 bfr = *(const bf16x8*)&WqF[(t * 8 + s) * 512 + lane * 8];
      qacc[t] = __builtin_amdgcn_mfma_f32_16x16x32_bf16(af, bfr, qacc[t], 0, 0, 0);
    }
  }
  f32x4 qvv, bkv;
  #pragma unroll
  for (int t = 0; t < 4; ++t) {
    qvv[t] = qacc[t][0] + bq[t * 16 + n16];
    bkv[t] = bk[t * 16 + n16];
  }
  // small per-row operands
  f32x4 w0 = *(const f32x4*)(nwts + gr * KNBR + 0);
  f32x4 w1 = *(const f32x4*)(nwts + gr * KNBR + 4);
  f32x4 w2 = *(const f32x4*)(nwts + gr * KNBR + 8);
  f32x4 w3 = *(const f32x4*)(nwts + gr * KNBR + 12);

  asm volatile("s_waitcnt vmcnt(0)" ::: "memory");   // neighbor DMAs landed

  // ---- 4. k-projection from f32 LDS, on-the-fly cvt (r11-verified) ----
  f32x4 kacc[4];
  #pragma unroll
  for (int t = 0; t < 4; ++t) { kacc[t][0]=0.f; kacc[t][1]=0.f; kacc[t][2]=0.f; kacc[t][3]=0.f; }
  const int xr = (n16 & 7) << 2;
  #pragma unroll
  for (int s = 0; s < 8; ++s) {
    const int c0 = s * 32 + g4 * 8;
    f32x4 a0 = *(const f32x4*)&sNbrF[w * 4096 + n16 * 256 + (c0 ^ xr)];
    f32x4 a1 = *(const f32x4*)&sNbrF[w * 4096 + n16 * 256 + ((c0 + 4) ^ xr)];
    bf16x8 af;
    af[0]=f2bf(a0[0]); af[1]=f2bf(a0[1]); af[2]=f2bf(a0[2]); af[3]=f2bf(a0[3]);
    af[4]=f2bf(a1[0]); af[5]=f2bf(a1[1]); af[6]=f2bf(a1[2]); af[7]=f2bf(a1[3]);
    #pragma unroll
    for (int t = 0; t < 4; ++t) {
      bf16x8 bfr = *(const bf16x8*)&WkF[(t * 8 + s) * 512 + lane * 8];
      kacc[t] = __builtin_amdgcn_mfma_f32_16x16x32_bf16(af, bfr, kacc[t], 0, 0, 0);
    }
  }

  // ---- 5. logits / softmax / reweight (r11-verified) ----
  f32x4 part;
  part[0]=0.f; part[1]=0.f; part[2]=0.f; part[3]=0.f;
  #pragma unroll
  for (int t = 0; t < 4; ++t) {
    #pragma unroll
    for (int r = 0; r < 4; ++r) part[r] += qvv[t] * (kacc[t][r] + bkv[t]);
  }
  #pragma unroll
  for (int off = 1; off < 16; off <<= 1) {
    #pragma unroll
    for (int r = 0; r < 4; ++r) part[r] += __shfl_xor(part[r], off);
  }
  f32x4 lg[4];
  #pragma unroll
  for (int j = 0; j < 16; ++j)
    lg[j >> 2][j & 3] = 0.125f * __shfl(part[j & 3], (j >> 2) << 4);
  float mx = -1e30f;
  #pragma unroll
  for (int j = 0; j < 16; ++j) mx = fmaxf(mx, lg[j >> 2][j & 3]);
  float sum = 0.f;
  #pragma unroll
  for (int j = 0; j < 16; ++j) {
    const float e = __expf(lg[j >> 2][j & 3] - mx);
    lg[j >> 2][j & 3] = e; sum += e;
  }
  const float rs = 1.f / sum;
  float den = 1e-8f;
  #pragma unroll
  for (int e = 0; e < 4; ++e) {
    lg[0][e] *= rs * w0[e]; den += lg[0][e];
    lg[1][e] *= rs * w1[e]; den += lg[1][e];
    lg[2][e] *= rs * w2[e]; den += lg[2][e];
    lg[3][e] *= rs * w3[e]; den += lg[3][e];
  }
  const float rd = 1.f / den;

  // ---- 6. context from f32 LDS (r11-verified) -> sGate ctx-half ----
  f32x4 cx;
  cx[0]=0.f; cx[1]=0.f; cx[2]=0.f; cx[3]=0.f;
  #pragma unroll
  for (int j = 0; j < 16; ++j) {
    f32x4 nv = *(const f32x4*)&sNbrF[w * 4096 + j * 256 + ((lane * 4) ^ ((j & 7) << 2))];
    const float aj = lg[j >> 2][j & 3];
    cx[0] += aj * nv[0]; cx[1] += aj * nv[1];
    cx[2] += aj * nv[2]; cx[3] += aj * nv[3];
  }
  {
    short4v co;
    co[0] = f2bf(cx[0] * rd); co[1] = f2bf(cx[1] * rd);
    co[2] = f2bf(cx[2] * rd); co[3] = f2bf(cx[3] * rd);
    *(short4v*)&sGate[(w * 512 + 256 + lane * 4) ^ (w << 3)] = co;
  }
  __syncthreads();   // sGate rows 0-3 complete (single barrier)

  // ---- 7. gate GEMM, M=4 padded (r10-verified) ----
  f32x4 gacc[4];
  #pragma unroll
  for (int t = 0; t < 4; ++t) { gacc[t][0]=0.f; gacc[t][1]=0.f; gacc[t][2]=0.f; gacc[t][3]=0.f; }
  #pragma unroll
  for (int s = 0; s < 16; ++s) {
    const int cr = n16 & 3;
    bf16x8 af = *(const bf16x8*)&sGate[(cr * 512 + s * 32 + g4 * 8) ^ (cr << 3)];
    #pragma unroll
    for (int tt = 0; tt < 4; ++tt) {
      bf16x8 bfr = *(const bf16x8*)&WgF[((w * 4 + tt) * 16 + s) * 512 + lane * 8];
      gacc[tt] = __builtin_amdgcn_mfma_f32_16x16x32_bf16(af, bfr, gacc[tt], 0, 0, 0);
    }
  }
  // ---- 8. epilogue: rows 0-3 live at g4==0 (r10-verified) ----
  if (g4 == 0) {
    #pragma unroll
    for (int tt = 0; tt < 4; ++tt) {
      const int dout = (w * 4 + tt) * 16 + n16;
      const float bga = bg[dout];
      #pragma unroll
      for (int r = 0; r < 4; ++r) {
        const size_t grr = (size_t)(row0 + r);
        const float pre  = gacc[tt][r] + bga;
        const float gate = 1.f / (1.f + __expf(-pre));
        const float cen  = center[grr * DDIM + dout];               // L2-hot
        const float cxv  = bf2f(sGate[(r * 512 + 256 + dout) ^ (r << 3)]);
        const float fused = gate * cen + (1.f - gate) * cxv;
        const bool valid = maskIsByte ? (mb[grr] != 0)
                                      : (((const unsigned int*)vmask)[grr] != 0u);
        out[grr * DDIM + dout] = valid ? fused : cen;
      }
    }
  }
}

// ================= fallback (ws too small): VERBATIM r8 fused kernel =================
__global__ __launch_bounds__(NTHREADS, 3)
void natt_fb(const float* __restrict__ center, const float* __restrict__ neigh,
             const float* __restrict__ nwts, const void* __restrict__ vmask,
             const float* __restrict__ Wq, const float* __restrict__ bq,
             const float* __restrict__ Wk, const float* __restrict__ bk,
             const float* __restrict__ Wg, const float* __restrict__ bg,
             float* __restrict__ out) {
  __shared__ __align__(16) short smem[24576];
  const int tid  = threadIdx.x;
  const int lane = tid & 63;
  const int w    = tid >> 6;
  const int n16  = lane & 15;
  const int g4   = lane >> 4;
  const int row0 = blockIdx.x * 16;
  const unsigned char* mb = (const unsigned char*)vmask;

  const unsigned char x1 = mb[lane * 4 + 1];
  const unsigned char x2 = mb[lane * 4 + 2];
  const unsigned char x3 = mb[lane * 4 + 3];
  const bool anyGe2 = __ballot((x1 >= 2) || (x2 >= 2) || (x3 >= 2)) != 0ULL;
  const bool anyNz  = __ballot(((x1 | x2) | x3) != 0) != 0ULL;
  const bool maskIsByte = anyNz && !anyGe2;

  #pragma unroll
  for (int it = 0; it < 4; ++it) {
    const int row = it * 4 + w;
    const int d   = lane * 4;
    float4 v = *(const float4*)(center + (size_t)(row0 + row) * DDIM + d);
    short4v o;
    o[0] = f2bf(v.x); o[1] = f2bf(v.y); o[2] = f2bf(v.z); o[3] = f2bf(v.w);
    *(short4v*)&smem[16384 + ((row * 512 + d) ^ ((row & 7) << 3))] = o;
  }
  __syncthreads();

  f32x4 qacc[4];
  #pragma unroll
  for (int t = 0; t < 4; ++t) { qacc[t][0]=0.f; qacc[t][1]=0.f; qacc[t][2]=0.f; qacc[t][3]=0.f; }
  #pragma unroll
  for (int s = 0; s < 8; ++s) {
    bf16x8 af = *(const bf16x8*)&smem[16384 + ((n16 * 512 + s * 32 + g4 * 8) ^ ((n16 & 7) << 3))];
    #pragma unroll
    for (int t = 0; t < 4; ++t) {
      bf16x8 bfr = ldWfrag(Wq, DDIM, t * 16 + n16, s * 32 + g4 * 8);
      qacc[t] = __builtin_amdgcn_mfma_f32_16x16x32_bf16(af, bfr, qacc[t], 0, 0, 0);
    }
  }
  f32x4 bqv, bkv;
  #pragma unroll
  for (int t = 0; t < 4; ++t) { bqv[t] = bq[t * 16 + n16]; bkv[t] = bk[t * 16 + n16]; }

  for (int rr = 0; rr < 4; ++rr) {
    const int rowl = w * 4 + rr;
    const size_t gr = (size_t)(row0 + rowl);
    const float4* np = (const float4*)(neigh + gr * (size_t)(KNBR * DDIM));
    {
      float4 vb[8];
      #pragma unroll
      for (int j = 0; j < 8; ++j) vb[j] = np[j * 64 + lane];
      #pragma unroll
      for (int j = 0; j < 8; ++j) {
        short4v o;
        o[0]=f2bf(vb[j].x); o[1]=f2bf(vb[j].y); o[2]=f2bf(vb[j].z); o[3]=f2bf(vb[j].w);
        *(short4v*)&smem[w * 4096 + ((j * 256 + lane * 4) ^ ((j & 7) << 3))] = o;
      }
      #pragma unroll
      for (int j = 0; j < 8; ++j) vb[j] = np[(j + 8) * 64 + lane];
      #pragma unroll
      for (int j = 0; j < 8; ++j) {
        short4v o;
        o[0]=f2bf(vb[j].x); o[1]=f2bf(vb[j].y); o[2]=f2bf(vb[j].z); o[3]=f2bf(vb[j].w);
        *(short4v*)&smem[w * 4096 + (((j + 8) * 256 + lane * 4) ^ (((j + 8) & 7) << 3))] = o;
      }
    }
    f32x4 kacc[4];
    #pragma unroll
    for (int t = 0; t < 4; ++t) { kacc[t][0]=0.f; kacc[t][1]=0.f; kacc[t][2]=0.f; kacc[t][3]=0.f; }
    #pragma unroll
    for (int s = 0; s < 8; ++s) {
      bf16x8 af = *(const bf16x8*)&smem[w * 4096 +
                    ((n16 * 256 + s * 32 + g4 * 8) ^ ((n16 & 7) << 3))];
      #pragma unroll
      for (int t = 0; t < 4; ++t) {
        bf16x8 bfr = ldWfrag(Wk, DDIM, t * 16 + n16, s * 32 + g4 * 8);
        kacc[t] = __builtin_amdgcn_mfma_f32_16x16x32_bf16(af, bfr, kacc[t], 0, 0, 0);
      }
    }
    f32x4 part;
    part[0]=0.f; part[1]=0.f; part[2]=0.f; part[3]=0.f;
    #pragma unroll
    for (int t = 0; t < 4; ++t) {
      float qv = qacc[t][0];
      if (rr == 1) qv = qacc[t][1];
      if (rr == 2) qv = qacc[t][2];
      if (rr == 3) qv = qacc[t][3];
      qv = __shfl(qv + bqv[t], w * 16 + n16);
      #pragma unroll
      for (int r = 0; r < 4; ++r) part[r] += qv * (kacc[t][r] + bkv[t]);
    }
    #pragma unroll
    for (int off = 1; off < 16; off <<= 1) {
      #pragma unroll
      for (int r = 0; r < 4; ++r) part[r] += __shfl_xor(part[r], off);
    }
    f32x4 lg[4];
    #pragma unroll
    for (int j = 0; j < 16; ++j)
      lg[j >> 2][j & 3] = 0.125f * __shfl(part[j & 3], (j >> 2) << 4);
    float mx = -1e30f;
    #pragma unroll
    for (int j = 0; j < 16; ++j) mx = fmaxf(mx, lg[j >> 2][j & 3]);
    float sum = 0.f;
    #pragma unroll
    for (int j = 0; j < 16; ++j) {
      const float e = __expf(lg[j >> 2][j & 3] - mx);
      lg[j >> 2][j & 3] = e; sum += e;
    }
    const float rs = 1.f / sum;
    float den = 1e-8f;
    #pragma unroll
    for (int q4 = 0; q4 < 4; ++q4) {
      f32x4 wvq = *(const f32x4*)(nwts + gr * KNBR + q4 * 4);
      #pragma unroll
      for (int e = 0; e < 4; ++e) { const float a = lg[q4][e] * rs * wvq[e]; lg[q4][e] = a; den += a; }
    }
    const float rd = 1.f / den;
    f32x4 cx;
    cx[0]=0.f; cx[1]=0.f; cx[2]=0.f; cx[3]=0.f;
    #pragma unroll
    for (int j = 0; j < 16; ++j) {
      short4v nv = *(const short4v*)&smem[w * 4096 + ((j * 256 + lane * 4) ^ ((j & 7) << 3))];
      const float aj = lg[j >> 2][j & 3];
      cx[0] += aj * bf2f(nv[0]); cx[1] += aj * bf2f(nv[1]);
      cx[2] += aj * bf2f(nv[2]); cx[3] += aj * bf2f(nv[3]);
    }
    short4v co;
    co[0] = f2bf(cx[0] * rd); co[1] = f2bf(cx[1] * rd);
    co[2] = f2bf(cx[2] * rd); co[3] = f2bf(cx[3] * rd);
    *(short4v*)&smem[16384 + ((rowl * 512 + 256 + lane * 4) ^ ((rowl & 7) << 3))] = co;
  }
  __syncthreads();

  f32x4 gacc[4];
  #pragma unroll
  for (int t = 0; t < 4; ++t) { gacc[t][0]=0.f; gacc[t][1]=0.f; gacc[t][2]=0.f; gacc[t][3]=0.f; }
  #pragma unroll
  for (int s = 0; s < 16; ++s) {
    bf16x8 af = *(const bf16x8*)&smem[16384 + ((n16 * 512 + s * 32 + g4 * 8) ^ ((n16 & 7) << 3))];
    #pragma unroll
    for (int tt = 0; tt < 4; ++tt) {
      bf16x8 bfr = ldWfrag(Wg, TWOD, (w * 4 + tt) * 16 + n16, s * 32 + g4 * 8);
      gacc[tt] = __builtin_amdgcn_mfma_f32_16x16x32_bf16(af, bfr, gacc[tt], 0, 0, 0);
    }
  }
  #pragma unroll
  for (int tt = 0; tt < 4; ++tt) {
    const int dout = (w * 4 + tt) * 16 + n16;
    const float bga = bg[dout];
    #pragma unroll
    for (int r = 0; r < 4; ++r) {
      const int rowl = g4 * 4 + r;
      const size_t gr = (size_t)(row0 + rowl);
      const float pre  = gacc[tt][r] + bga;
      const float gate = 1.f / (1.f + __expf(-pre));
      const float cen  = center[gr * DDIM + dout];
      const float cxv  = bf2f(smem[16384 + ((rowl * 512 + 256 + dout) ^ ((rowl & 7) << 3))]);
      const float fused = gate * cen + (1.f - gate) * cxv;
      const bool valid = maskIsByte ? (mb[gr] != 0)
                                    : (((const unsigned int*)vmask)[gr] != 0u);
      out[gr * DDIM + dout] = valid ? fused : cen;
    }
  }
}

extern "C" void kernel_launch(void* const* d_in, const int* in_sizes, int n_in,
                              void* d_out, int out_size, void* d_ws, size_t ws_size,
                              hipStream_t stream) {
  const float* center = (const float*)d_in[0];
  const float* neigh  = (const float*)d_in[1];
  const float* nwts   = (const float*)d_in[2];
  const void*  vm     = d_in[3];
  const float* Wq = (const float*)d_in[4];
  const float* bq = (const float*)d_in[5];
  const float* Wk = (const float*)d_in[6];
  const float* bk = (const float*)d_in[7];
  const float* Wg = (const float*)d_in[8];
  const float* bg = (const float*)d_in[9];
  float* out = (float*)d_out;

  const int nrows = in_sizes[0] / DDIM;           // 32768
  dim3 block(NTHREADS);

  if (ws_size >= (size_t)WS_NEED) {
    short* WF = (short*)d_ws;
    hipLaunchKernelGGL(prep_frags, dim3(80), block, 0, stream, Wq, Wk, Wg, WF);
    hipLaunchKernelGGL(natt_one, dim3(nrows / 4), block, 0, stream,
                       center, neigh, nwts, vm, WF, bq, bk, bg, out);
  } else {
    hipLaunchKernelGGL(natt_fb, dim3(nrows / 16), block, 0, stream,
                       center, neigh, nwts, vm, Wq, bq, Wk, bk, Wg, bg, out);
  }
}

// Round 14
// 184.894 us; speedup vs baseline: 1.4892x; 1.4892x over previous
//
#include <hip/hip_runtime.h>
#include <hip/hip_bf16.h>

#define DDIM   256
#define KNBR   16
#define TWOD   512
#define NTHREADS 256

using bf16x8  = __attribute__((ext_vector_type(8))) short;
using short4v = __attribute__((ext_vector_type(4))) short;
using f32x4   = __attribute__((ext_vector_type(4))) float;

// ---- ws layout: WF shorts [0,163840) | ctxg bf16 [32768][256]
#define CTX_SOFF 163840u
#define WS_NEED  17104896u

__device__ __forceinline__ short f2bf(float x) {
  unsigned int u;
  __builtin_memcpy(&u, &x, 4);
  u += 0x7FFFu + ((u >> 16) & 1u);   // RNE
  return (short)(u >> 16);
}
__device__ __forceinline__ float bf2f(short s) {
  unsigned int u = ((unsigned int)(unsigned short)s) << 16;
  float f;
  __builtin_memcpy(&f, &u, 4);
  return f;
}

// Verified B-fragment loader (fallback path only)
__device__ __forceinline__ bf16x8 ldWfrag(const float* __restrict__ W, int ld, int r, int c) {
  const float4* p = (const float4*)(W + (size_t)r * ld + c);
  float4 a = p[0];
  float4 b = p[1];
  bf16x8 o;
  o[0] = f2bf(a.x); o[1] = f2bf(a.y); o[2] = f2bf(a.z); o[3] = f2bf(a.w);
  o[4] = f2bf(b.x); o[5] = f2bf(b.y); o[6] = f2bf(b.z); o[7] = f2bf(b.w);
  return o;
}

// ---- prep_frags: VERBATIM (HW-passed). WqF(32) WkF(32) WgF(256) ----
__global__ void prep_frags(const float* __restrict__ Wq,
                           const float* __restrict__ Wk,
                           const float* __restrict__ Wg,
                           short* __restrict__ F) {
  const int gid  = blockIdx.x * NTHREADS + threadIdx.x;
  const int lane = gid & 63;
  const int n16  = lane & 15;
  const int g4   = lane >> 4;
  const int f    = gid >> 6;                 // 0..319
  const float* src;
  short* dst;
  if (f < 32) {
    const int t = f >> 3, s = f & 7;
    src = Wq + (size_t)(t * 16 + n16) * DDIM + s * 32 + g4 * 8;
    dst = F + f * 512 + lane * 8;
  } else if (f < 64) {
    const int fq = f - 32;
    const int t = fq >> 3, s = fq & 7;
    src = Wk + (size_t)(t * 16 + n16) * DDIM + s * 32 + g4 * 8;
    dst = F + 16384 + fq * 512 + lane * 8;
  } else {
    const int fg = f - 64;                   // 0..255
    const int t4 = fg >> 4, s = fg & 15;
    src = Wg + (size_t)(t4 * 16 + n16) * TWOD + s * 32 + g4 * 8;
    dst = F + 32768 + fg * 512 + lane * 8;
  }
  float4 a = *(const float4*)src;
  float4 b = *(const float4*)(src + 4);
  bf16x8 o;
  o[0] = f2bf(a.x); o[1] = f2bf(a.y); o[2] = f2bf(a.z); o[3] = f2bf(a.w);
  o[4] = f2bf(b.x); o[5] = f2bf(b.y); o[6] = f2bf(b.z); o[7] = f2bf(b.w);
  *(bf16x8*)dst = o;
}

// ==================== Kernel A: r9 ctx2 + r12 own-row q-proj (k_q folded in) ====================
// LDS: sNbr 32KB (4 waves x [16][256] bf16 swz) + sCen [4][256] bf16 swz (2KB)
__global__ __launch_bounds__(NTHREADS, 3)
void natt_ctx2p(const float* __restrict__ center, const float* __restrict__ neigh,
                const float* __restrict__ nwts, const short* __restrict__ WF,
                const float* __restrict__ bq, const float* __restrict__ bk,
                short* __restrict__ ctxg) {
  __shared__ __align__(16) short sNbr[16384];
  __shared__ __align__(16) short sCen[1024];
  const int tid  = threadIdx.x;
  const int lane = tid & 63;
  const int w    = tid >> 6;
  const int n16  = lane & 15;
  const int g4   = lane >> 4;
  const size_t gr = (size_t)blockIdx.x * 4 + w;
  const short* WqF = WF;
  const short* WkF = WF + 16384;

  // ---- 1. issue the 16 KB/wave neighbor burst FIRST (r9-verified lever) ----
  const float4* np = (const float4*)(neigh + gr * (size_t)(KNBR * DDIM));
  float4 nb0 = np[0*64+lane], nb1 = np[1*64+lane], nb2 = np[2*64+lane], nb3 = np[3*64+lane];
  float4 nb4 = np[4*64+lane], nb5 = np[5*64+lane], nb6 = np[6*64+lane], nb7 = np[7*64+lane];
  float4 nb8 = np[8*64+lane], nb9 = np[9*64+lane], nbA = np[10*64+lane], nbB = np[11*64+lane];
  float4 nbC = np[12*64+lane], nbD = np[13*64+lane], nbE = np[14*64+lane], nbF = np[15*64+lane];

  // ---- 2. own center row -> sCen (r12-verified) ----
  {
    float4 cv = *(const float4*)(center + gr * DDIM + lane * 4);
    short4v o;
    o[0] = f2bf(cv.x); o[1] = f2bf(cv.y); o[2] = f2bf(cv.z); o[3] = f2bf(cv.w);
    *(short4v*)&sCen[(w * 256 + lane * 4) ^ (w << 3)] = o;
  }

  // ---- 3. own-row q-projection (r12-verified; overlaps burst latency; no barrier) ----
  f32x4 qacc[4];
  #pragma unroll
  for (int t = 0; t < 4; ++t) { qacc[t][0]=0.f; qacc[t][1]=0.f; qacc[t][2]=0.f; qacc[t][3]=0.f; }
  #pragma unroll
  for (int s = 0; s < 8; ++s) {
    bf16x8 af = *(const bf16x8*)&sCen[(w * 256 + s * 32 + g4 * 8) ^ (w << 3)];  // wave-uniform row
    #pragma unroll
    for (int t = 0; t < 4; ++t) {
      bf16x8 bfr = *(const bf16x8*)&WqF[(t * 8 + s) * 512 + lane * 8];
      qacc[t] = __builtin_amdgcn_mfma_f32_16x16x32_bf16(af, bfr, qacc[t], 0, 0, 0);
    }
  }
  f32x4 qvv, bkv;
  #pragma unroll
  for (int t = 0; t < 4; ++t) {
    qvv[t] = qacc[t][0] + bq[t * 16 + n16];
    bkv[t] = bk[t * 16 + n16];
  }
  f32x4 w0 = *(const f32x4*)(nwts + gr * KNBR + 0);
  f32x4 w1 = *(const f32x4*)(nwts + gr * KNBR + 4);
  f32x4 w2 = *(const f32x4*)(nwts + gr * KNBR + 8);
  f32x4 w3 = *(const f32x4*)(nwts + gr * KNBR + 12);

  // ---- 4. stage neighbors to LDS bf16 swz (r9-verified) ----
  #define STG(j, v) { short4v o_;                                                   \
    o_[0]=f2bf((v).x); o_[1]=f2bf((v).y); o_[2]=f2bf((v).z); o_[3]=f2bf((v).w);     \
    *(short4v*)&sNbr[w * 4096 + (((j) * 256 + lane * 4) ^ (((j) & 7) << 3))] = o_; }
  STG(0,nb0)  STG(1,nb1)  STG(2,nb2)  STG(3,nb3)
  STG(4,nb4)  STG(5,nb5)  STG(6,nb6)  STG(7,nb7)
  STG(8,nb8)  STG(9,nb9)  STG(10,nbA) STG(11,nbB)
  STG(12,nbC) STG(13,nbD) STG(14,nbE) STG(15,nbF)
  #undef STG

  // ---- 5. k-projection: M=16 neighbors, N=64, K=256 (r9-verified) ----
  f32x4 kacc[4];
  #pragma unroll
  for (int t = 0; t < 4; ++t) { kacc[t][0]=0.f; kacc[t][1]=0.f; kacc[t][2]=0.f; kacc[t][3]=0.f; }
  #pragma unroll
  for (int s = 0; s < 8; ++s) {
    bf16x8 af = *(const bf16x8*)&sNbr[w * 4096 +
                  ((n16 * 256 + s * 32 + g4 * 8) ^ ((n16 & 7) << 3))];
    #pragma unroll
    for (int t = 0; t < 4; ++t) {
      bf16x8 bfr = *(const bf16x8*)&WkF[(t * 8 + s) * 512 + lane * 8];
      kacc[t] = __builtin_amdgcn_mfma_f32_16x16x32_bf16(af, bfr, kacc[t], 0, 0, 0);
    }
  }

  // ---- 6. logits / softmax / reweight (r9-verified) ----
  f32x4 part;
  part[0]=0.f; part[1]=0.f; part[2]=0.f; part[3]=0.f;
  #pragma unroll
  for (int t = 0; t < 4; ++t) {
    #pragma unroll
    for (int r = 0; r < 4; ++r) part[r] += qvv[t] * (kacc[t][r] + bkv[t]);
  }
  #pragma unroll
  for (int off = 1; off < 16; off <<= 1) {
    #pragma unroll
    for (int r = 0; r < 4; ++r) part[r] += __shfl_xor(part[r], off);
  }
  f32x4 lg[4];
  #pragma unroll
  for (int j = 0; j < 16; ++j)
    lg[j >> 2][j & 3] = 0.125f * __shfl(part[j & 3], (j >> 2) << 4);
  float mx = -1e30f;
  #pragma unroll
  for (int j = 0; j < 16; ++j) mx = fmaxf(mx, lg[j >> 2][j & 3]);
  float sum = 0.f;
  #pragma unroll
  for (int j = 0; j < 16; ++j) {
    const float e = __expf(lg[j >> 2][j & 3] - mx);
    lg[j >> 2][j & 3] = e; sum += e;
  }
  const float rs = 1.f / sum;
  float den = 1e-8f;
  #pragma unroll
  for (int e = 0; e < 4; ++e) {
    lg[0][e] *= rs * w0[e]; den += lg[0][e];
    lg[1][e] *= rs * w1[e]; den += lg[1][e];
    lg[2][e] *= rs * w2[e]; den += lg[2][e];
    lg[3][e] *= rs * w3[e]; den += lg[3][e];
  }
  const float rd = 1.f / den;

  // ---- 7. context from LDS (r9-verified) -> ctxg ----
  f32x4 cx;
  cx[0]=0.f; cx[1]=0.f; cx[2]=0.f; cx[3]=0.f;
  #pragma unroll
  for (int j = 0; j < 16; ++j) {
    short4v nv = *(const short4v*)&sNbr[w * 4096 + ((j * 256 + lane * 4) ^ ((j & 7) << 3))];
    const float aj = lg[j >> 2][j & 3];
    cx[0] += aj * bf2f(nv[0]); cx[1] += aj * bf2f(nv[1]);
    cx[2] += aj * bf2f(nv[2]); cx[3] += aj * bf2f(nv[3]);
  }
  short4v co;
  co[0] = f2bf(cx[0] * rd); co[1] = f2bf(cx[1] * rd);
  co[2] = f2bf(cx[2] * rd); co[3] = f2bf(cx[3] * rd);
  *(short4v*)(ctxg + gr * DDIM + lane * 4) = co;
}

// ==================== Kernel B: gate GEMM + epilogue (VERBATIM r9, HW-passed) ====================
__global__ __launch_bounds__(NTHREADS, 4)
void natt_gate(const float* __restrict__ center, const short* __restrict__ ctxg,
               const void* __restrict__ vmask, const short* __restrict__ WF,
               const float* __restrict__ bg, float* __restrict__ out) {
  __shared__ __align__(16) short sCen[4096];
  __shared__ __align__(16) short sCtx[4096];
  const int tid  = threadIdx.x;
  const int lane = tid & 63;
  const int w    = tid >> 6;
  const int n16  = lane & 15;
  const int g4   = lane >> 4;
  const int row0 = blockIdx.x * 16;
  const unsigned char* mb = (const unsigned char*)vmask;
  const short* WgF = WF + 32768;

  const unsigned char x1 = mb[lane * 4 + 1];
  const unsigned char x2 = mb[lane * 4 + 2];
  const unsigned char x3 = mb[lane * 4 + 3];
  const bool anyGe2 = __ballot((x1 >= 2) || (x2 >= 2) || (x3 >= 2)) != 0ULL;
  const bool anyNz  = __ballot(((x1 | x2) | x3) != 0) != 0ULL;
  const bool maskIsByte = anyNz && !anyGe2;

  #pragma unroll
  for (int it = 0; it < 4; ++it) {
    const int row = it * 4 + w;
    const int d   = lane * 4;
    float4 v = *(const float4*)(center + (size_t)(row0 + row) * DDIM + d);
    short4v o;
    o[0] = f2bf(v.x); o[1] = f2bf(v.y); o[2] = f2bf(v.z); o[3] = f2bf(v.w);
    *(short4v*)&sCen[(row * 256 + d) ^ ((row & 7) << 3)] = o;
    short4v cv = *(const short4v*)(ctxg + (size_t)(row0 + row) * DDIM + d);
    *(short4v*)&sCtx[(row * 256 + d) ^ ((row & 7) << 3)] = cv;
  }
  __syncthreads();

  f32x4 gacc[4];
  #pragma unroll
  for (int t = 0; t < 4; ++t) { gacc[t][0]=0.f; gacc[t][1]=0.f; gacc[t][2]=0.f; gacc[t][3]=0.f; }
  #pragma unroll
  for (int s = 0; s < 16; ++s) {
    bf16x8 af;
    if (s < 8) {
      af = *(const bf16x8*)&sCen[(n16 * 256 + s * 32 + g4 * 8) ^ ((n16 & 7) << 3)];
    } else {
      af = *(const bf16x8*)&sCtx[(n16 * 256 + (s - 8) * 32 + g4 * 8) ^ ((n16 & 7) << 3)];
    }
    #pragma unroll
    for (int tt = 0; tt < 4; ++tt) {
      bf16x8 bfr = *(const bf16x8*)&WgF[((w * 4 + tt) * 16 + s) * 512 + lane * 8];
      gacc[tt] = __builtin_amdgcn_mfma_f32_16x16x32_bf16(af, bfr, gacc[tt], 0, 0, 0);
    }
  }
  #pragma unroll
  for (int tt = 0; tt < 4; ++tt) {
    const int dout = (w * 4 + tt) * 16 + n16;
    const float bga = bg[dout];
    #pragma unroll
    for (int r = 0; r < 4; ++r) {
      const int rowl = g4 * 4 + r;
      const size_t gr = (size_t)(row0 + rowl);
      const float pre  = gacc[tt][r] + bga;
      const float gate = 1.f / (1.f + __expf(-pre));
      const float cen  = center[gr * DDIM + dout];
      const float cxv  = bf2f(sCtx[(rowl * 256 + dout) ^ ((rowl & 7) << 3)]);
      const float fused = gate * cen + (1.f - gate) * cxv;
      const bool valid = maskIsByte ? (mb[gr] != 0)
                                    : (((const unsigned int*)vmask)[gr] != 0u);
      out[gr * DDIM + dout] = valid ? fused : cen;
    }
  }
}

// ================= fallback (ws too small): VERBATIM r8 fused kernel =================
__global__ __launch_bounds__(NTHREADS, 3)
void natt_fb(const float* __restrict__ center, const float* __restrict__ neigh,
             const float* __restrict__ nwts, const void* __restrict__ vmask,
             const float* __restrict__ Wq, const float* __restrict__ bq,
             const float* __restrict__ Wk, const float* __restrict__ bk,
             const float* __restrict__ Wg, const float* __restrict__ bg,
             float* __restrict__ out) {
  __shared__ __align__(16) short smem[24576];
  const int tid  = threadIdx.x;
  const int lane = tid & 63;
  const int w    = tid >> 6;
  const int n16  = lane & 15;
  const int g4   = lane >> 4;
  const int row0 = blockIdx.x * 16;
  const unsigned char* mb = (const unsigned char*)vmask;

  const unsigned char x1 = mb[lane * 4 + 1];
  const unsigned char x2 = mb[lane * 4 + 2];
  const unsigned char x3 = mb[lane * 4 + 3];
  const bool anyGe2 = __ballot((x1 >= 2) || (x2 >= 2) || (x3 >= 2)) != 0ULL;
  const bool anyNz  = __ballot(((x1 | x2) | x3) != 0) != 0ULL;
  const bool maskIsByte = anyNz && !anyGe2;

  #pragma unroll
  for (int it = 0; it < 4; ++it) {
    const int row = it * 4 + w;
    const int d   = lane * 4;
    float4 v = *(const float4*)(center + (size_t)(row0 + row) * DDIM + d);
    short4v o;
    o[0] = f2bf(v.x); o[1] = f2bf(v.y); o[2] = f2bf(v.z); o[3] = f2bf(v.w);
    *(short4v*)&smem[16384 + ((row * 512 + d) ^ ((row & 7) << 3))] = o;
  }
  __syncthreads();

  f32x4 qacc[4];
  #pragma unroll
  for (int t = 0; t < 4; ++t) { qacc[t][0]=0.f; qacc[t][1]=0.f; qacc[t][2]=0.f; qacc[t][3]=0.f; }
  #pragma unroll
  for (int s = 0; s < 8; ++s) {
    bf16x8 af = *(const bf16x8*)&smem[16384 + ((n16 * 512 + s * 32 + g4 * 8) ^ ((n16 & 7) << 3))];
    #pragma unroll
    for (int t = 0; t < 4; ++t) {
      bf16x8 bfr = ldWfrag(Wq, DDIM, t * 16 + n16, s * 32 + g4 * 8);
      qacc[t] = __builtin_amdgcn_mfma_f32_16x16x32_bf16(af, bfr, qacc[t], 0, 0, 0);
    }
  }
  f32x4 bqv, bkv;
  #pragma unroll
  for (int t = 0; t < 4; ++t) { bqv[t] = bq[t * 16 + n16]; bkv[t] = bk[t * 16 + n16]; }

  for (int rr = 0; rr < 4; ++rr) {
    const int rowl = w * 4 + rr;
    const size_t gr = (size_t)(row0 + rowl);
    const float4* np = (const float4*)(neigh + gr * (size_t)(KNBR * DDIM));
    {
      float4 vb[8];
      #pragma unroll
      for (int j = 0; j < 8; ++j) vb[j] = np[j * 64 + lane];
      #pragma unroll
      for (int j = 0; j < 8; ++j) {
        short4v o;
        o[0]=f2bf(vb[j].x); o[1]=f2bf(vb[j].y); o[2]=f2bf(vb[j].z); o[3]=f2bf(vb[j].w);
        *(short4v*)&smem[w * 4096 + ((j * 256 + lane * 4) ^ ((j & 7) << 3))] = o;
      }
      #pragma unroll
      for (int j = 0; j < 8; ++j) vb[j] = np[(j + 8) * 64 + lane];
      #pragma unroll
      for (int j = 0; j < 8; ++j) {
        short4v o;
        o[0]=f2bf(vb[j].x); o[1]=f2bf(vb[j].y); o[2]=f2bf(vb[j].z); o[3]=f2bf(vb[j].w);
        *(short4v*)&smem[w * 4096 + (((j + 8) * 256 + lane * 4) ^ (((j + 8) & 7) << 3))] = o;
      }
    }
    f32x4 kacc[4];
    #pragma unroll
    for (int t = 0; t < 4; ++t) { kacc[t][0]=0.f; kacc[t][1]=0.f; kacc[t][2]=0.f; kacc[t][3]=0.f; }
    #pragma unroll
    for (int s = 0; s < 8; ++s) {
      bf16x8 af = *(const bf16x8*)&smem[w * 4096 +
                    ((n16 * 256 + s * 32 + g4 * 8) ^ ((n16 & 7) << 3))];
      #pragma unroll
      for (int t = 0; t < 4; ++t) {
        bf16x8 bfr = ldWfrag(Wk, DDIM, t * 16 + n16, s * 32 + g4 * 8);
        kacc[t] = __builtin_amdgcn_mfma_f32_16x16x32_bf16(af, bfr, kacc[t], 0, 0, 0);
      }
    }
    f32x4 part;
    part[0]=0.f; part[1]=0.f; part[2]=0.f; part[3]=0.f;
    #pragma unroll
    for (int t = 0; t < 4; ++t) {
      float qv = qacc[t][0];
      if (rr == 1) qv = qacc[t][1];
      if (rr == 2) qv = qacc[t][2];
      if (rr == 3) qv = qacc[t][3];
      qv = __shfl(qv + bqv[t], w * 16 + n16);
      #pragma unroll
      for (int r = 0; r < 4; ++r) part[r] += qv * (kacc[t][r] + bkv[t]);
    }
    #pragma unroll
    for (int off = 1; off < 16; off <<= 1) {
      #pragma unroll
      for (int r = 0; r < 4; ++r) part[r] += __shfl_xor(part[r], off);
    }
    f32x4 lg[4];
    #pragma unroll
    for (int j = 0; j < 16; ++j)
      lg[j >> 2][j & 3] = 0.125f * __shfl(part[j & 3], (j >> 2) << 4);
    float mx = -1e30f;
    #pragma unroll
    for (int j = 0; j < 16; ++j) mx = fmaxf(mx, lg[j >> 2][j & 3]);
    float sum = 0.f;
    #pragma unroll
    for (int j = 0; j < 16; ++j) {
      const float e = __expf(lg[j >> 2][j & 3] - mx);
      lg[j >> 2][j & 3] = e; sum += e;
    }
    const float rs = 1.f / sum;
    float den = 1e-8f;
    #pragma unroll
    for (int q4 = 0; q4 < 4; ++q4) {
      f32x4 wvq = *(const f32x4*)(nwts + gr * KNBR + q4 * 4);
      #pragma unroll
      for (int e = 0; e < 4; ++e) { const float a = lg[q4][e] * rs * wvq[e]; lg[q4][e] = a; den += a; }
    }
    const float rd = 1.f / den;
    f32x4 cx;
    cx[0]=0.f; cx[1]=0.f; cx[2]=0.f; cx[3]=0.f;
    #pragma unroll
    for (int j = 0; j < 16; ++j) {
      short4v nv = *(const short4v*)&smem[w * 4096 + ((j * 256 + lane * 4) ^ ((j & 7) << 3))];
      const float aj = lg[j >> 2][j & 3];
      cx[0] += aj * bf2f(nv[0]); cx[1] += aj * bf2f(nv[1]);
      cx[2] += aj * bf2f(nv[2]); cx[3] += aj * bf2f(nv[3]);
    }
    short4v co;
    co[0] = f2bf(cx[0] * rd); co[1] = f2bf(cx[1] * rd);
    co[2] = f2bf(cx[2] * rd); co[3] = f2bf(cx[3] * rd);
    *(short4v*)&smem[16384 + ((rowl * 512 + 256 + lane * 4) ^ ((rowl & 7) << 3))] = co;
  }
  __syncthreads();

  f32x4 gacc[4];
  #pragma unroll
  for (int t = 0; t < 4; ++t) { gacc[t][0]=0.f; gacc[t][1]=0.f; gacc[t][2]=0.f; gacc[t][3]=0.f; }
  #pragma unroll
  for (int s = 0; s < 16; ++s) {
    bf16x8 af = *(const bf16x8*)&smem[16384 + ((n16 * 512 + s * 32 + g4 * 8) ^ ((n16 & 7) << 3))];
    #pragma unroll
    for (int tt = 0; tt < 4; ++tt) {
      bf16x8 bfr = ldWfrag(Wg, TWOD, (w * 4 + tt) * 16 + n16, s * 32 + g4 * 8);
      gacc[tt] = __builtin_amdgcn_mfma_f32_16x16x32_bf16(af, bfr, gacc[tt], 0, 0, 0);
    }
  }
  #pragma unroll
  for (int tt = 0; tt < 4; ++tt) {
    const int dout = (w * 4 + tt) * 16 + n16;
    const float bga = bg[dout];
    #pragma unroll
    for (int r = 0; r < 4; ++r) {
      const int rowl = g4 * 4 + r;
      const size_t gr = (size_t)(row0 + rowl);
      const float pre  = gacc[tt][r] + bga;
      const float gate = 1.f / (1.f + __expf(-pre));
      const float cen  = center[gr * DDIM + dout];
      const float cxv  = bf2f(smem[16384 + ((rowl * 512 + 256 + dout) ^ ((rowl & 7) << 3))]);
      const float fused = gate * cen + (1.f - gate) * cxv;
      const bool valid = maskIsByte ? (mb[gr] != 0)
                                    : (((const unsigned int*)vmask)[gr] != 0u);
      out[gr * DDIM + dout] = valid ? fused : cen;
    }
  }
}

extern "C" void kernel_launch(void* const* d_in, const int* in_sizes, int n_in,
                              void* d_out, int out_size, void* d_ws, size_t ws_size,
                              hipStream_t stream) {
  const float* center = (const float*)d_in[0];
  const float* neigh  = (const float*)d_in[1];
  const float* nwts   = (const float*)d_in[2];
  const void*  vm     = d_in[3];
  const float* Wq = (const float*)d_in[4];
  const float* bq = (const float*)d_in[5];
  const float* Wk = (const float*)d_in[6];
  const float* bk = (const float*)d_in[7];
  const float* Wg = (const float*)d_in[8];
  const float* bg = (const float*)d_in[9];
  float* out = (float*)d_out;

  const int nrows = in_sizes[0] / DDIM;           // 32768
  dim3 block(NTHREADS);

  if (ws_size >= (size_t)WS_NEED) {
    short* WF   = (short*)d_ws;
    short* ctxg = WF + CTX_SOFF;
    hipLaunchKernelGGL(prep_frags, dim3(80), block, 0, stream, Wq, Wk, Wg, WF);
    hipLaunchKernelGGL(natt_ctx2p, dim3(nrows / 4), block, 0, stream,
                       center, neigh, nwts, WF, bq, bk, ctxg);
    hipLaunchKernelGGL(natt_gate, dim3(nrows / 16), block, 0, stream,
                       center, ctxg, vm, WF, bg, out);
  } else {
    hipLaunchKernelGGL(natt_fb, dim3(nrows / 16), block, 0, stream,
                       center, neigh, nwts, vm, Wq, bq, Wk, bk, Wg, bg, out);
  }
}